// Round 9
// baseline (179.397 us; speedup 1.0000x reference)
//
#include <hip/hip_runtime.h>

#define N_NODES 100000
#define N_EDGES 1600000
#define D_FEAT 64

#define RB_LOG 6
#define ROWS_PER_BUCKET 64
#define N_BUCKET ((N_NODES + ROWS_PER_BUCKET - 1) / ROWS_PER_BUCKET)  // 1563

#define COL_BITS 17
#define COL_MASK ((1 << COL_BITS) - 1)

#define NBLK 256       // == CU count: 1 block/CU, all co-resident by construction
#define NTHR 1024
#define STILE 6250     // 256 * 6250 = 1,600,000 exactly
#define SEPT 7         // ceil(6250/1024)
#define NT 256         // tiles == blocks
#define NTCOL 256      // boffT row stride
#define CAP_R 1536     // per-bucket recbuf; mean 1024, +16 sigma
#define GROUPS 4       // gather groups per block (256 thr each)

#define N_PACK (N_NODES * D_FEAT / 8)   // 800000 uint4 of bf16 H

// ---- LDS union layout (static 62.6 KB; scatter view / gather view) --------
#define L_STAGE   0          // int2[6250]            = 50000 -> pad 50048
#define L_HIST    50048      // int[1563]             =  6252 -> pad 56320
#define L_LBASE   56320      // int[1564]             =  6256 -> end  62576
#define L_RECBUF  0          // int2[4*1536]          = 49152
#define L_RSTART  49152      // int[4*65]             =  1040 -> pad 50240
#define L_RCUR    50240      // int[4*64]             =  1024
#define L_SBUF    51264      // int[4*2*64]           =  2048 -> end  53312
#define LDS_BYTES 62592

__device__ __forceinline__ unsigned f2bf(float x) {
    unsigned u = __float_as_uint(x);
    return (u + 0x7fffu + ((u >> 16) & 1u)) >> 16;
}

// accumulate 8 bf16 features (one uint4) into two float4 accumulators
__device__ __forceinline__ void fma8(float v, uint4 u, float4& p, float4& q) {
    p.x += v * __uint_as_float(u.x << 16);
    p.y += v * __uint_as_float(u.x & 0xffff0000u);
    p.z += v * __uint_as_float(u.y << 16);
    p.w += v * __uint_as_float(u.y & 0xffff0000u);
    q.x += v * __uint_as_float(u.z << 16);
    q.y += v * __uint_as_float(u.z & 0xffff0000u);
    q.z += v * __uint_as_float(u.w << 16);
    q.w += v * __uint_as_float(u.w & 0xffff0000u);
}

__global__ __launch_bounds__(NTHR, 1) void fused_kernel(
    const float* __restrict__ vals, const int* __restrict__ rows,
    const int* __restrict__ cols, const float* __restrict__ H,
    unsigned* __restrict__ HB, int2* __restrict__ rec2,
    int* __restrict__ boffT, int* __restrict__ bar,
    float* __restrict__ out)
{
    __shared__ alignas(16) char lds[LDS_BYTES];

    int tid = threadIdx.x;
    int bid = blockIdx.x;

    // ================= phase A: H -> bf16 (grid-strided) ===================
    {
        const float4* H4 = reinterpret_cast<const float4*>(H);
        uint4* HB4 = reinterpret_cast<uint4*>(HB);
        for (int t = bid * NTHR + tid; t < N_PACK; t += NBLK * NTHR) {
            float4 a = H4[2 * t], b = H4[2 * t + 1];
            uint4 o;
            o.x = (f2bf(a.y) << 16) | f2bf(a.x);
            o.y = (f2bf(a.w) << 16) | f2bf(a.z);
            o.z = (f2bf(b.y) << 16) | f2bf(b.x);
            o.w = (f2bf(b.w) << 16) | f2bf(b.z);
            HB4[t] = o;
        }
    }

    // ================= phase B: scatter (tile bid, deterministic) ==========
    {
        int2* stage = reinterpret_cast<int2*>(lds + L_STAGE);
        int*  hist  = reinterpret_cast<int*>(lds + L_HIST);
        int*  lbase = reinterpret_cast<int*>(lds + L_LBASE);

        for (int i = tid; i < N_BUCKET; i += NTHR) hist[i] = 0;
        __syncthreads();

        int t0 = bid * STILE;
        int er[SEPT], ec[SEPT], eb[SEPT], rk[SEPT];
        float ev[SEPT];
        #pragma unroll
        for (int j = 0; j < SEPT; ++j) {
            int el = j * NTHR + tid;
            if (el < STILE) {
                int e = t0 + el;
                er[j] = rows[e]; ec[j] = cols[e]; ev[j] = vals[e];
                eb[j] = er[j] >> RB_LOG;
                rk[j] = atomicAdd(&hist[eb[j]], 1);
            } else {
                eb[j] = -1;
            }
        }
        __syncthreads();

        // exclusive scan (chunk of 2) using stage head as ping-pong buffer
        int* ss = reinterpret_cast<int*>(stage);
        int c0 = (2 * tid     < N_BUCKET) ? hist[2 * tid]     : 0;
        int c1 = (2 * tid + 1 < N_BUCKET) ? hist[2 * tid + 1] : 0;
        ss[tid] = c0 + c1;
        __syncthreads();
        int sel = 0;
        for (int off = 1; off < NTHR; off <<= 1) {
            int x = ss[sel * NTHR + tid];
            if (tid >= off) x += ss[sel * NTHR + tid - off];
            ss[(1 - sel) * NTHR + tid] = x;
            __syncthreads();
            sel ^= 1;
        }
        int run = tid ? ss[sel * NTHR + tid - 1] : 0;
        if (2 * tid     <= N_BUCKET) lbase[2 * tid]     = run;
        if (2 * tid + 1 <= N_BUCKET) lbase[2 * tid + 1] = run + c0;
        __syncthreads();   // scan buffer dead; stage reusable

        // publish per-tile offsets (bucket-major: gather reads contiguous)
        for (int i = tid; i <= N_BUCKET; i += NTHR)
            boffT[i * NTCOL + bid] = lbase[i];

        // place records bucket-sorted into stage
        #pragma unroll
        for (int j = 0; j < SEPT; ++j) {
            if (eb[j] >= 0) {
                stage[lbase[eb[j]] + rk[j]] = make_int2(
                    ((er[j] & (ROWS_PER_BUCKET - 1)) << COL_BITS) | ec[j],
                    __float_as_int(ev[j]));
            }
        }
        __syncthreads();

        // linear coalesced copy-out (6250 int2 = 3125 int4 exactly)
        const int4* s4 = reinterpret_cast<const int4*>(stage);
        int4* d4 = reinterpret_cast<int4*>(rec2 + (size_t)t0);
        for (int i = tid; i < STILE / 2; i += NTHR) d4[i] = s4[i];
    }

    // ================= grid barrier (device-scope) =========================
    __syncthreads();
    if (tid == 0) {
        __threadfence();                       // release rec2/boffT/HB
        atomicAdd(bar, 1);
        while (atomicAdd(bar, 0) < NBLK) __builtin_amdgcn_s_sleep(2);
        __threadfence();                       // acquire
    }
    __syncthreads();

    // ================= phase C: gather (4 groups x 256 thr) ================
    {
        int2* recbuf = reinterpret_cast<int2*>(lds + L_RECBUF);
        int*  rstart = reinterpret_cast<int*>(lds + L_RSTART);
        int*  rcur   = reinterpret_cast<int*>(lds + L_RCUR);
        int*  sbuf   = reinterpret_cast<int*>(lds + L_SBUF);

        int g  = tid >> 8;        // group 0..3
        int gt = tid & 255;       // thread within group
        int rg = gt >> 2;         // row 0..63
        int f  = gt & 3;          // feature-slice lane
        const uint4* HB4 = reinterpret_cast<const uint4*>(HB);

        for (int rd = 0; rd < 2; ++rd) {
            int b = bid * GROUPS + g + rd * (NBLK * GROUPS);
            bool vb = (b < N_BUCKET);

            if (gt < ROWS_PER_BUCKET) rcur[g * 64 + gt] = 0;
            int tb = 0, te = 0;
            if (vb) {
                tb = boffT[b * NTCOL + gt];
                te = boffT[(b + 1) * NTCOL + gt];
            }
            __syncthreads();

            // pass 1: walk segment `gt`, count rows
            const int2* seg = rec2 + (size_t)gt * STILE;
            for (int i = tb; i < te; ++i)
                atomicAdd(&rcur[g * 64 + (seg[i].x >> COL_BITS)], 1);
            __syncthreads();

            // scan 64 counts per group -> rstart
            if (gt < ROWS_PER_BUCKET) sbuf[(g * 2) * 64 + gt] = rcur[g * 64 + gt];
            __syncthreads();
            int sel = 0;
            for (int off = 1; off < ROWS_PER_BUCKET; off <<= 1) {
                if (gt < ROWS_PER_BUCKET) {
                    int x = sbuf[(g * 2 + sel) * 64 + gt];
                    if (gt >= off) x += sbuf[(g * 2 + sel) * 64 + gt - off];
                    sbuf[(g * 2 + (1 - sel)) * 64 + gt] = x;
                }
                __syncthreads();
                sel ^= 1;
            }
            if (gt < ROWS_PER_BUCKET) rstart[g * 65 + gt + 1] = sbuf[(g * 2 + sel) * 64 + gt];
            if (gt == 0) rstart[g * 65] = 0;
            __syncthreads();
            if (gt < ROWS_PER_BUCKET) rcur[g * 64 + gt] = rstart[g * 65 + gt];
            __syncthreads();

            // pass 2: re-read segment (L2-hot), place row-sorted
            for (int i = tb; i < te; ++i) {
                int2 r = seg[i];
                int pos = atomicAdd(&rcur[g * 64 + (r.x >> COL_BITS)], 1);
                if (pos < CAP_R) recbuf[g * CAP_R + pos] = r;
            }
            __syncthreads();

            // register-accumulate row rg (bf16 H), unroll 4
            float4 acc[4];
            #pragma unroll
            for (int q = 0; q < 4; ++q) acc[q] = make_float4(0.f, 0.f, 0.f, 0.f);
            {
                int s = rstart[g * 65 + rg];
                int e2 = rstart[g * 65 + rg + 1];
                if (e2 > CAP_R) e2 = CAP_R;
                const int2* rb = recbuf + g * CAP_R;
                int i = s;
                for (; i + 4 <= e2; i += 4) {
                    int2 r0 = rb[i],     r1 = rb[i + 1];
                    int2 r2 = rb[i + 2], r3 = rb[i + 3];
                    int c0 = (r0.x & COL_MASK) * 8, c1 = (r1.x & COL_MASK) * 8;
                    int c2 = (r2.x & COL_MASK) * 8, c3 = (r3.x & COL_MASK) * 8;
                    uint4 a0 = HB4[c0 + f], b0 = HB4[c0 + 4 + f];
                    uint4 a1 = HB4[c1 + f], b1 = HB4[c1 + 4 + f];
                    uint4 a2 = HB4[c2 + f], b2 = HB4[c2 + 4 + f];
                    uint4 a3 = HB4[c3 + f], b3 = HB4[c3 + 4 + f];
                    float v0 = __int_as_float(r0.y), v1 = __int_as_float(r1.y);
                    float v2 = __int_as_float(r2.y), v3 = __int_as_float(r3.y);
                    fma8(v0, a0, acc[0], acc[1]); fma8(v0, b0, acc[2], acc[3]);
                    fma8(v1, a1, acc[0], acc[1]); fma8(v1, b1, acc[2], acc[3]);
                    fma8(v2, a2, acc[0], acc[1]); fma8(v2, b2, acc[2], acc[3]);
                    fma8(v3, a3, acc[0], acc[1]); fma8(v3, b3, acc[2], acc[3]);
                }
                for (; i < e2; ++i) {
                    int2 r0 = rb[i];
                    int c0 = (r0.x & COL_MASK) * 8;
                    uint4 a0 = HB4[c0 + f], b0 = HB4[c0 + 4 + f];
                    float v0 = __int_as_float(r0.y);
                    fma8(v0, a0, acc[0], acc[1]); fma8(v0, b0, acc[2], acc[3]);
                }
            }

            // coalesced writeback
            int row = b * ROWS_PER_BUCKET + rg;
            if (vb && row < N_NODES) {
                float4* o4 = reinterpret_cast<float4*>(out);
                o4[row * 16 + 2 * f]         = acc[0];
                o4[row * 16 + 2 * f + 1]     = acc[1];
                o4[row * 16 + 8 + 2 * f]     = acc[2];
                o4[row * 16 + 8 + 2 * f + 1] = acc[3];
            }
            __syncthreads();   // recbuf/rcur reuse safety for round 2
        }
    }
}

extern "C" void kernel_launch(void* const* d_in, const int* in_sizes, int n_in,
                              void* d_out, int out_size, void* d_ws, size_t ws_size,
                              hipStream_t stream) {
    const float* H    = (const float*)d_in[0];
    const float* vals = (const float*)d_in[1];
    const int*   rows = (const int*)d_in[2];
    const int*   cols = (const int*)d_in[3];
    float* out = (float*)d_out;

    char* ws = (char*)ws_size ? (char*)d_ws : (char*)d_ws;
    int2* rec2  = (int2*)d_ws;                                   // 12.8 MB
    int*  boffT = (int*)(rec2 + (size_t)NT * STILE);             // 1564*256*4 = 1.6 MB
    unsigned* HB = (unsigned*)(boffT + (size_t)(N_BUCKET + 1) * NTCOL);  // 12.8 MB
    int* bar = (int*)(HB + (size_t)N_NODES * D_FEAT);            // 16 ints

    hipMemsetAsync(bar, 0, 64, stream);
    fused_kernel<<<NBLK, NTHR, 0, stream>>>(
        vals, rows, cols, H, HB, rec2, boffT, bar, out);
}